// Round 8
// baseline (342.335 us; speedup 1.0000x reference)
//
#include <hip/hip_runtime.h>
#include <hip/hip_bf16.h>

typedef unsigned char  u8_t;
typedef unsigned short u16_t;
typedef unsigned int   u32_t;
typedef __attribute__((ext_vector_type(8))) short bf16x8;
typedef __attribute__((ext_vector_type(4))) float f32x4;
typedef __attribute__((ext_vector_type(16))) float f32x16;

#define HW2  36864   // 192*192
#define NTOK 2304    // tokens per 48x48 window

__device__ __forceinline__ u32_t cvtpk(float a, float b) {
    union { __hip_bfloat162 h; u32_t u; } c;
    c.h = __float22bfloat162_rn(float2{a, b});
    return c.u;
}
__device__ __forceinline__ float bfhi(u32_t u) { union { u32_t u; float f; } c; c.u = u & 0xffff0000u; return c.f; }
__device__ __forceinline__ float bflo(u32_t u) { union { u32_t u; float f; } c; c.u = u << 16; return c.f; }

union U8x { u32_t u[4]; bf16x8 v; };
union F16x { float4 f4[4]; f32x16 v; };

#define MF32(A, B, C) __builtin_amdgcn_mfma_f32_32x32x16_bf16(A, B, C, 0, 0, 0)

// ---- MFMA projections: even blocks = Q from x; odd blocks = K,V,mask from ref ----
__global__ __launch_bounds__(256) void proj_kernel(
    const float* __restrict__ x, const float* __restrict__ ref, const float* __restrict__ unc,
    const float* __restrict__ ipw, const float* __restrict__ ipb,
    u16_t* __restrict__ Q, u16_t* __restrict__ K, u16_t* __restrict__ Vt, float* __restrict__ Uf)
{
    __shared__ u32_t Tt[64][33];
    const int side = blockIdx.x & 1;             // 0: Q,  1: K/V
    const int hb = blockIdx.x >> 1;              // 0..575
    const int bid = (hb & 7) * 72 + (hb >> 3);   // XCD-bijective (576%8==0)
    const int tokb = bid * 64;
    const int win = tokb / NTOK;
    const int n0 = tokb - win * NTOK;

    const int w = threadIdx.x >> 6;
    const int lane = threadIdx.x & 63;
    const int tile = w & 1;
    const int sel = w >> 1;                      // Q: octile; KV: 0=K 1=V
    const int q = lane & 31;
    const int hi = lane >> 5;

    const float* in = side ? ref : x;
    int n = n0 + tile * 32 + q;
    int p = ((win >> 2) * 48 + n / 48) * 192 + (win & 3) * 48 + n % 48;

    // B-frags: 4 k-chunks of 16 channels, gathered per-channel (coalesced across lanes)
    bf16x8 bfr[4];
    #pragma unroll
    for (int kc = 0; kc < 4; ++kc) {
        float v[8];
        #pragma unroll
        for (int i = 0; i < 8; ++i) v[i] = in[(size_t)(kc * 16 + hi * 8 + i) * HW2 + p];
        U8x pk;
        #pragma unroll
        for (int j = 0; j < 4; ++j) pk.u[j] = cvtpk(v[2 * j], v[2 * j + 1]);
        bfr[kc] = pk.v;
    }

    if (side == 0) {
        const float SCL = 0.18033688011112043f;   // log2(e)/8
        const int oct = sel;
        f32x16 acc;
        #pragma unroll
        for (int r = 0; r < 16; ++r)
            acc[r] = ipb[oct * 32 + (r & 3) + 8 * (r >> 2) + 4 * hi] * SCL;
        #pragma unroll
        for (int kc = 0; kc < 4; ++kc) {
            const float* wr = ipw + (size_t)(oct * 32 + q) * 64 + kc * 16 + hi * 8;
            U8x a;
            #pragma unroll
            for (int j = 0; j < 4; ++j) a.u[j] = cvtpk(wr[2 * j] * SCL, wr[2 * j + 1] * SCL);
            acc = MF32(a.v, bfr[kc], acc);
        }
        #pragma unroll
        for (int rp = 0; rp < 8; ++rp) {
            int j = (rp & 1) + ((rp >> 1) << 2) + 2 * hi + (oct << 4);
            Tt[tile * 32 + q][j] = cvtpk(acc[2 * rp], acc[2 * rp + 1]);
        }
    } else if (sel == 0) {
        #pragma unroll
        for (int oct = 0; oct < 2; ++oct) {
            f32x16 acc;
            #pragma unroll
            for (int r = 0; r < 16; ++r)
                acc[r] = ipb[64 + oct * 32 + (r & 3) + 8 * (r >> 2) + 4 * hi];
            #pragma unroll
            for (int kc = 0; kc < 4; ++kc) {
                const float* wr = ipw + (size_t)(64 + oct * 32 + q) * 64 + kc * 16 + hi * 8;
                U8x a;
                #pragma unroll
                for (int j = 0; j < 4; ++j) a.u[j] = cvtpk(wr[2 * j], wr[2 * j + 1]);
                acc = MF32(a.v, bfr[kc], acc);
            }
            #pragma unroll
            for (int rp = 0; rp < 8; ++rp) {
                int j = (rp & 1) + ((rp >> 1) << 2) + 2 * hi + (oct << 4);
                Tt[tile * 32 + q][j] = cvtpk(acc[2 * rp], acc[2 * rp + 1]);
            }
        }
    } else {
        // V: transposed + token-permuted scattered stores; plus mask
        int sub = (q >> 2) & 7;
        int pq = (((sub ^ (sub >> 1)) & 1) ? (q ^ 12) : q);
        u16_t* vb = Vt + (size_t)win * 64 * NTOK + n0 + tile * 32 + pq;
        #pragma unroll
        for (int oct = 0; oct < 2; ++oct) {
            f32x16 acc;
            #pragma unroll
            for (int r = 0; r < 16; ++r)
                acc[r] = ipb[128 + oct * 32 + (r & 3) + 8 * (r >> 2) + 4 * hi];
            #pragma unroll
            for (int kc = 0; kc < 4; ++kc) {
                const float* wr = ipw + (size_t)(128 + oct * 32 + q) * 64 + kc * 16 + hi * 8;
                U8x a;
                #pragma unroll
                for (int j = 0; j < 4; ++j) a.u[j] = cvtpk(wr[2 * j], wr[2 * j + 1]);
                acc = MF32(a.v, bfr[kc], acc);
            }
            #pragma unroll
            for (int r = 0; r < 16; ++r) {
                int ch = oct * 32 + (r & 3) + 8 * (r >> 2) + 4 * hi;
                vb[(size_t)ch * NTOK] = (u16_t)(cvtpk(acc[r], 0.f) & 0xffffu);
            }
        }
        if (hi == 0) Uf[tokb + tile * 32 + q] = (unc[p] > 0.01f) ? 0.f : -100.f;
    }
    __syncthreads();

    // coalesced store of Tt -> Q or K  ([tok][64] bf16)
    {
        u16_t* dst = side ? K : Q;
        int tok = threadIdx.x >> 2, s8 = (threadIdx.x & 3) * 8;
        u32_t v0[4], v1[4];
        #pragma unroll
        for (int j = 0; j < 4; ++j) { v0[j] = Tt[tok][s8 + j]; v1[j] = Tt[tok][s8 + 4 + j]; }
        u32_t* d = (u32_t*)(dst + (size_t)(tokb + tok) * 64) + s8;
        *(uint4*)d       = uint4{v0[0], v0[1], v0[2], v0[3]};
        *(uint4*)(d + 4) = uint4{v1[0], v1[1], v1[2], v1[3]};
    }
}

// ---- prep + meanV: b0 = fold out_proj*w1; b1..36 = conv weight pack; b37..100 = meanV from Vt ----
__global__ __launch_bounds__(256) void prepmv_kernel(
    const float* __restrict__ wop, const float* __restrict__ bop,
    const float* __restrict__ w1, const float* __restrict__ b1,
    const float* __restrict__ w3, const u16_t* __restrict__ Vt,
    float* __restrict__ Wc, float* __restrict__ bc, u16_t* __restrict__ Wpk,
    float* __restrict__ meanV)
{
    __shared__ float red[16][17];
    int tid = threadIdx.x;
    if (blockIdx.x == 0) {
        for (int idx = tid; idx < 4096; idx += 256) {
            int f = idx >> 6, d = idx & 63;
            float a = 0.f;
            for (int e = 0; e < 64; ++e) a += w1[f * 64 + e] * wop[e * 64 + d];
            Wc[idx] = a;
        }
        if (tid < 64) {
            float a = b1[tid];
            for (int e = 0; e < 64; ++e) a += w1[tid * 64 + e] * bop[e];
            bc[tid] = a;
        }
    } else if (blockIdx.x < 37) {
        for (int idx = (blockIdx.x - 1) * 256 + tid; idx < 36864; idx += 9216) {
            int i = idx & 7;
            int lane = (idx >> 3) & 63;
            int t2 = idx >> 9;
            int ks = t2 % 18, mf = t2 / 18;
            int oc = mf * 16 + (lane & 15);
            int g = lane >> 4;
            int tap = ks >> 1, icc = ks & 1;
            int dy = tap / 3, dx = tap - (tap / 3) * 3;
            int ic = icc * 32 + g * 8 + i;
            Wpk[idx] = (u16_t)(cvtpk(w3[(size_t)(oc * 64 + ic) * 9 + dy * 3 + dx], 0.f) & 0xffffu);
        }
    } else {
        int m = blockIdx.x - 37;
        int win = m >> 2, cq = m & 3;
        int chl = tid >> 4, seg = tid & 15;
        const uint2* src = (const uint2*)(Vt + (size_t)win * 64 * NTOK + (size_t)(cq * 16 + chl) * NTOK + seg * 144);
        float s = 0.f;
        for (int i = 0; i < 36; ++i) {      // 36 uint2 = 144 tokens per segment
            uint2 v = src[i];
            s += bflo(v.x) + bfhi(v.x) + bflo(v.y) + bfhi(v.y);
        }
        red[chl][seg] = s;
        __syncthreads();
        if (tid < 16) {
            float a = 0.f;
            #pragma unroll
            for (int k = 0; k < 16; ++k) a += red[tid][k];
            meanV[win * 64 + cq * 16 + tid] = a * (1.f / 2304.f);
        }
    }
}

// ---- attention: 32 q-rows/block, split-K x4, 1152 blocks; mask as MFMA-C bias ----
__global__ __launch_bounds__(256, 4) void attn_kernel(
    const u16_t* __restrict__ Q, const u16_t* __restrict__ K, const u16_t* __restrict__ Vt,
    const float* __restrict__ Uf, const float* __restrict__ meanV, u16_t* __restrict__ Oatt)
{
    __shared__ float Ored[4][32][68];
    __shared__ float Lred[4][32];

    const int bid = (blockIdx.x & 7) * 144 + (blockIdx.x >> 3);   // XCD-bijective (1152%8==0)
    const int lane = threadIdx.x & 63;
    const int kq = threadIdx.x >> 6;
    const int q  = lane & 31;
    const int hi = lane >> 5;
    const int win = bid / 72;
    const int rg  = bid % 72;
    const int row0 = rg * 32;

    const u16_t* Qw = Q + (size_t)win * NTOK * 64;
    const u16_t* Kw = K + (size_t)win * NTOK * 64;
    const u16_t* Vw = Vt + (size_t)win * 64 * NTOK;
    const float* Uw = Uf + win * NTOK;

    bf16x8 qb[4];
    #pragma unroll
    for (int s = 0; s < 4; ++s)
        qb[s] = *(const bf16x8*)(Qw + (size_t)(row0 + q) * 64 + s * 16 + hi * 8);

    const f32x16 Z16 = {0.f,0.f,0.f,0.f,0.f,0.f,0.f,0.f,0.f,0.f,0.f,0.f,0.f,0.f,0.f,0.f};
    f32x16 acc0 = Z16, acc1 = Z16;
    float lsum = 0.f;

    const u16_t* kp = Kw + (size_t)(kq * 576 + q) * 64 + hi * 8;
    const u16_t* vp = Vw + (size_t)q * NTOK + kq * 576 + hi * 8;
    const float* up = Uw + kq * 576 + 4 * hi;

    bf16x8 kA0,kA1,kA2,kA3, vA0,vA1,vA2,vA3;
    bf16x8 kB0,kB1,kB2,kB3, vB0,vB1,vB2,vB3;
    F16x bA, bB;

#define LDSET(sfx, CT) { \
    const u16_t* _k = kp + (size_t)(CT) * 2048; \
    k##sfx##0 = *(const bf16x8*)(_k);      k##sfx##1 = *(const bf16x8*)(_k + 16); \
    k##sfx##2 = *(const bf16x8*)(_k + 32); k##sfx##3 = *(const bf16x8*)(_k + 48); \
    const u16_t* _v = vp + (CT) * 32; \
    v##sfx##0 = *(const bf16x8*)(_v);             v##sfx##1 = *(const bf16x8*)(_v + 16); \
    v##sfx##2 = *(const bf16x8*)(_v + 32 * NTOK); v##sfx##3 = *(const bf16x8*)(_v + 32 * NTOK + 16); \
    const float* _u = up + (CT) * 32; \
    b##sfx.f4[0] = *(const float4*)(_u);      b##sfx.f4[1] = *(const float4*)(_u + 8); \
    b##sfx.f4[2] = *(const float4*)(_u + 16); b##sfx.f4[3] = *(const float4*)(_u + 24); }

#define QS_TILE(sfx) { \
    f32x16 s = b##sfx.v; \
    s = MF32(k##sfx##0, qb[0], s); s = MF32(k##sfx##1, qb[1], s); \
    s = MF32(k##sfx##2, qb[2], s); s = MF32(k##sfx##3, qb[3], s); \
    float pv[16]; float lls = 0.f; \
    _Pragma("unroll") for (int r = 0; r < 16; ++r) { pv[r] = __builtin_exp2f(s[r]); lls += pv[r]; } \
    lsum += lls; \
    U8x f0, f1; \
    _Pragma("unroll") for (int j = 0; j < 4; ++j) { \
        f0.u[j] = cvtpk(pv[2 * j], pv[2 * j + 1]); \
        f1.u[j] = cvtpk(pv[8 + 2 * j], pv[8 + 2 * j + 1]); } \
    acc0 = MF32(v##sfx##0, f0.v, acc0); acc0 = MF32(v##sfx##1, f1.v, acc0); \
    acc1 = MF32(v##sfx##2, f0.v, acc1); acc1 = MF32(v##sfx##3, f1.v, acc1); }

    LDSET(A, 0)
    #pragma unroll 1
    for (int tt = 0; tt < 9; ++tt) {
        LDSET(B, 2 * tt + 1)
        QS_TILE(A)
        if (tt < 8) LDSET(A, 2 * tt + 2)
        QS_TILE(B)
    }
#undef QS_TILE
#undef LDSET

    lsum += __shfl_xor(lsum, 32);
    if (hi == 0) Lred[kq][q] = lsum;

    #pragma unroll
    for (int rr = 0; rr < 4; ++rr) {
        float4 v0 = { acc0[4*rr], acc0[4*rr+1], acc0[4*rr+2], acc0[4*rr+3] };
        float4 v1 = { acc1[4*rr], acc1[4*rr+1], acc1[4*rr+2], acc1[4*rr+3] };
        *(float4*)&Ored[kq][q][8 * rr + 4 * hi]      = v0;
        *(float4*)&Ored[kq][q][32 + 8 * rr + 4 * hi] = v1;
    }
    __syncthreads();

    const int qr = threadIdx.x >> 3;
    const int ch0 = (threadIdx.x & 7) * 8;
    float o[8] = {0.f,0.f,0.f,0.f,0.f,0.f,0.f,0.f};
    #pragma unroll
    for (int w = 0; w < 4; ++w) {
        float4 a = *(float4*)&Ored[w][qr][ch0];
        float4 b = *(float4*)&Ored[w][qr][ch0 + 4];
        o[0] += a.x; o[1] += a.y; o[2] += a.z; o[3] += a.w;
        o[4] += b.x; o[5] += b.y; o[6] += b.z; o[7] += b.w;
    }
    float l = Lred[0][qr] + Lred[1][qr] + Lred[2][qr] + Lred[3][qr];
    float linv = (l > 0.f) ? 1.f / l : 0.f;
    int row = row0 + qr;
    uint4 wv;
    if (Uw[row] == 0.f) {   // uncertain row
        wv = uint4{ cvtpk(o[0]*linv, o[1]*linv), cvtpk(o[2]*linv, o[3]*linv),
                    cvtpk(o[4]*linv, o[5]*linv), cvtpk(o[6]*linv, o[7]*linv) };
    } else {
        const float* mv = meanV + win * 64 + ch0;
        wv = uint4{ cvtpk(mv[0], mv[1]), cvtpk(mv[2], mv[3]),
                    cvtpk(mv[4], mv[5]), cvtpk(mv[6], mv[7]) };
    }
    *(uint4*)(Oatt + (size_t)(win * NTOK + row) * 64 + ch0) = wv;
}

// ---- refined (bf16 NHWC [p][64]) = x + Oatt @ Wc^T + bc  — MFMA GEMM ----
__global__ __launch_bounds__(256) void refined_kernel(
    const float* __restrict__ x, const u16_t* __restrict__ Oatt,
    const float* __restrict__ Wc, const float* __restrict__ bc,
    u16_t* __restrict__ refd)
{
    __shared__ u32_t Tt[64][33];
    const int bid = (blockIdx.x & 7) * 72 + (blockIdx.x >> 3);   // 576 blocks
    const int tokb = bid * 64;
    const int win = tokb / NTOK;
    const int n0 = tokb - win * NTOK;

    const int w = threadIdx.x >> 6;
    const int lane = threadIdx.x & 63;
    const int tile = w & 1;
    const int oct = w >> 1;
    const int q = lane & 31;
    const int hi = lane >> 5;

    int n = n0 + tile * 32 + q;
    int p = ((win >> 2) * 48 + n / 48) * 192 + (win & 3) * 48 + n % 48;

    const u16_t* ob = Oatt + (size_t)(tokb + tile * 32 + q) * 64 + hi * 8;
    bf16x8 bfr[4];
    #pragma unroll
    for (int kc = 0; kc < 4; ++kc) bfr[kc] = *(const bf16x8*)(ob + kc * 16);

    f32x16 acc;
    #pragma unroll
    for (int r = 0; r < 16; ++r)
        acc[r] = bc[oct * 32 + (r & 3) + 8 * (r >> 2) + 4 * hi];
    #pragma unroll
    for (int kc = 0; kc < 4; ++kc) {
        const float* wr = Wc + (size_t)(oct * 32 + q) * 64 + kc * 16 + hi * 8;
        U8x a;
        #pragma unroll
        for (int j = 0; j < 4; ++j) a.u[j] = cvtpk(wr[2 * j], wr[2 * j + 1]);
        acc = MF32(a.v, bfr[kc], acc);
    }
    #pragma unroll
    for (int rp = 0; rp < 8; ++rp) {
        int ch = oct * 32 + (2 * rp & 3) + 8 * (rp >> 1) + 4 * hi;
        float xa = x[(size_t)ch * HW2 + p] + acc[2 * rp];
        float xb = x[(size_t)(ch + 1) * HW2 + p] + acc[2 * rp + 1];
        int j = (rp & 1) + ((rp >> 1) << 2) + 2 * hi + (oct << 4);
        Tt[tile * 32 + q][j] = cvtpk(xa, xb);
    }
    __syncthreads();

    {
        int tok = threadIdx.x >> 2, s8 = (threadIdx.x & 3) * 8;
        int nn = n0 + tok;
        int pp = ((win >> 2) * 48 + nn / 48) * 192 + (win & 3) * 48 + nn % 48;
        u32_t v0[4], v1[4];
        #pragma unroll
        for (int j = 0; j < 4; ++j) { v0[j] = Tt[tok][s8 + j]; v1[j] = Tt[tok][s8 + 4 + j]; }
        u32_t* d = (u32_t*)(refd + (size_t)pp * 64) + s8;
        *(uint4*)d       = uint4{v0[0], v0[1], v0[2], v0[3]};
        *(uint4*)(d + 4) = uint4{v1[0], v1[1], v1[2], v1[3]};
    }
}

// ------- conv3x3(+bias,relu)->out0, 1x1->out1, partition map; implicit-GEMM MFMA, NHWC in -------
__global__ __launch_bounds__(256) void conv_kernel(
    const u16_t* __restrict__ refined, const u16_t* __restrict__ Wpk,
    const float* __restrict__ b3, const float* __restrict__ w4, const float* __restrict__ b4,
    float* __restrict__ out0, float* __restrict__ out1, float* __restrict__ pm)
{
    __shared__ u16_t tile[3 * 50 * 64];    // [pix][ic], slot-swizzled; 19,200 B
    __shared__ float ps[48];
    int bid = (blockIdx.x & 7) * 96 + (blockIdx.x >> 3);
    const int y  = bid >> 2;
    const int x0 = (bid & 3) * 48;
    const int tid = threadIdx.x;
    if (tid < 48) ps[tid] = 0.f;

    for (int idx = tid; idx < 1200; idx += 256) {     // 150 pixels x 8 chunks
        int tg = idx & 7;
        int pix = idx >> 3;
        int r = pix / 50, cc = pix - r * 50;
        int yy = y - 1 + r, xg = x0 - 1 + cc;
        bf16x8 val = {0,0,0,0,0,0,0,0};
        if ((unsigned)yy < 192u && (unsigned)xg < 192u)
            val = *(const bf16x8*)(refined + ((size_t)(yy * 192 + xg)) * 64 + tg * 8);
        int slot = (tg + cc) & 7;
        *(bf16x8*)((char*)tile + (size_t)pix * 128 + slot * 16) = val;
    }
    __syncthreads();

    const int lane = tid & 63, mf = tid >> 6;
    const int ln = lane & 15, g = lane >> 4;

    bf16x8 wf[18];
    #pragma unroll
    for (int ks = 0; ks < 18; ++ks)
        wf[ks] = *(const bf16x8*)(Wpk + (size_t)((mf * 18 + ks) * 64 + lane) * 8);

    float b3v[4], w4v[4];
    #pragma unroll
    for (int r = 0; r < 4; ++r) { int oc = mf * 16 + 4 * g + r; b3v[r] = b3[oc]; w4v[r] = w4[oc]; }

    for (int nf = 0; nf < 3; ++nf) {
        int xl = nf * 16 + ln;
        f32x4 acc0 = {0.f,0.f,0.f,0.f}, acc1 = acc0;
        #pragma unroll
        for (int ks = 0; ks < 18; ++ks) {
            int tap = ks >> 1, icc = ks & 1;
            int dy = tap / 3, dx = tap - (tap / 3) * 3;
            int cc = xl + dx;
            int slot = (icc * 4 + g + cc) & 7;
            bf16x8 bfr = *(const bf16x8*)((const char*)tile + (size_t)(dy * 50 + cc) * 128 + slot * 16);
            if (ks & 1) acc1 = __builtin_amdgcn_mfma_f32_16x16x32_bf16(wf[ks], bfr, acc1, 0, 0, 0);
            else        acc0 = __builtin_amdgcn_mfma_f32_16x16x32_bf16(wf[ks], bfr, acc0, 0, 0, 0);
        }
        int xg = x0 + xl;
        float s4 = 0.f;
        #pragma unroll
        for (int r = 0; r < 4; ++r) {
            int oc = mf * 16 + 4 * g + r;
            float v = fmaxf(acc0[r] + acc1[r] + b3v[r], 0.f);
            out0[(size_t)oc * HW2 + y * 192 + xg] = v;
            s4 += v * w4v[r];
        }
        atomicAdd(&ps[xl], s4);
    }
    __syncthreads();
    if (tid < 48) {
        int xg = x0 + tid;
        out1[y * 192 + xg] = ps[tid] + b4[0];
        int ym = y % 48, xm = xg % 48;
        pm[y * 192 + xg] = ((ym == 0) | (ym == 47) | (xm == 0) | (xm == 47)) ? 0.6f : 1.0f;
    }
}

extern "C" void kernel_launch(void* const* d_in, const int* in_sizes, int n_in,
                              void* d_out, int out_size, void* d_ws, size_t ws_size,
                              hipStream_t stream)
{
    const float* x   = (const float*)d_in[0];
    const float* ref = (const float*)d_in[1];
    const float* unc = (const float*)d_in[2];
    const float* ipw = (const float*)d_in[3];
    const float* ipb = (const float*)d_in[4];
    const float* opw = (const float*)d_in[5];
    const float* opb = (const float*)d_in[6];
    const float* w1  = (const float*)d_in[7];
    const float* b1  = (const float*)d_in[8];
    const float* w3  = (const float*)d_in[9];
    const float* b3  = (const float*)d_in[10];
    const float* w4  = (const float*)d_in[11];
    const float* b4  = (const float*)d_in[12];

    char* ws = (char*)d_ws;
    u16_t* Qb    = (u16_t*)(ws);                  // 4,718,592
    u16_t* Kb    = (u16_t*)(ws + 4718592);        // 4,718,592
    u16_t* Vtb   = (u16_t*)(ws + 9437184);        // 4,718,592
    float* Ufp   = (float*)(ws + 14155776);       // 147,456
    float* meanV = (float*)(ws + 14303232);       // 4,096
    float* Wc    = (float*)(ws + 14307328);       // 16,384
    float* bc    = (float*)(ws + 14323712);       // 256
    u16_t* Wpk   = (u16_t*)(ws + 14323968);       // 73,728
    u16_t* Oatt  = (u16_t*)(ws + 14397696);       // 4,718,592
    u16_t* refd  = (u16_t*)(ws + 19116288);       // 4,718,592  (total 23,834,880 B)

    float* out0 = (float*)d_out;                  // r3: [1,64,192,192]
    float* out1 = out0 + 2359296;                 // out: [1,1,192,192]
    float* pmap = out0 + 2396160;                 // partition_map

    proj_kernel   <<<1152, 256, 0, stream>>>(x, ref, unc, ipw, ipb, Qb, Kb, Vtb, Ufp);
    prepmv_kernel <<<101,  256, 0, stream>>>(opw, opb, w1, b1, w3, Vtb, Wc, bc, Wpk, meanV);
    attn_kernel   <<<1152, 256, 0, stream>>>(Qb, Kb, Vtb, Ufp, meanV, Oatt);
    refined_kernel<<<576,  256, 0, stream>>>(x, Oatt, Wc, bc, refd);
    conv_kernel   <<<768,  256, 0, stream>>>(refd, Wpk, b3, w4, b4, out0, out1, pmap);
}

// Round 9
// 240.576 us; speedup vs baseline: 1.4230x; 1.4230x over previous
//
#include <hip/hip_runtime.h>
#include <hip/hip_bf16.h>

typedef unsigned char  u8_t;
typedef unsigned short u16_t;
typedef unsigned int   u32_t;
typedef __attribute__((ext_vector_type(8))) short bf16x8;
typedef __attribute__((ext_vector_type(4))) float f32x4;
typedef __attribute__((ext_vector_type(16))) float f32x16;

#define HW2  36864   // 192*192
#define NTOK 2304    // tokens per 48x48 window

__device__ __forceinline__ u32_t cvtpk(float a, float b) {
    union { __hip_bfloat162 h; u32_t u; } c;
    c.h = __float22bfloat162_rn(float2{a, b});
    return c.u;
}
__device__ __forceinline__ float bfhi(u32_t u) { union { u32_t u; float f; } c; c.u = u & 0xffff0000u; return c.f; }
__device__ __forceinline__ float bflo(u32_t u) { union { u32_t u; float f; } c; c.u = u << 16; return c.f; }

union U8x { u32_t u[4]; bf16x8 v; };
union F16x { float4 f4[4]; f32x16 v; };

#define MF32(A, B, C) __builtin_amdgcn_mfma_f32_32x32x16_bf16(A, B, C, 0, 0, 0)

// ---- MFMA projections: even blocks = Q from x; odd blocks = K,V,mask from ref ----
__global__ __launch_bounds__(256) void proj_kernel(
    const float* __restrict__ x, const float* __restrict__ ref, const float* __restrict__ unc,
    const float* __restrict__ ipw, const float* __restrict__ ipb,
    u16_t* __restrict__ Q, u16_t* __restrict__ K, u16_t* __restrict__ Vt, float* __restrict__ Uf)
{
    __shared__ u32_t Tt[64][33];
    const int side = blockIdx.x & 1;             // 0: Q,  1: K/V
    const int hb = blockIdx.x >> 1;              // 0..575
    const int bid = (hb & 7) * 72 + (hb >> 3);   // XCD-bijective (576%8==0)
    const int tokb = bid * 64;
    const int win = tokb / NTOK;
    const int n0 = tokb - win * NTOK;

    const int w = threadIdx.x >> 6;
    const int lane = threadIdx.x & 63;
    const int tile = w & 1;
    const int sel = w >> 1;                      // Q: octile; KV: 0=K 1=V
    const int q = lane & 31;
    const int hi = lane >> 5;

    const float* in = side ? ref : x;
    int n = n0 + tile * 32 + q;
    int p = ((win >> 2) * 48 + n / 48) * 192 + (win & 3) * 48 + n % 48;

    // B-frags: 4 k-chunks of 16 channels, gathered per-channel (coalesced across lanes)
    bf16x8 bfr[4];
    #pragma unroll
    for (int kc = 0; kc < 4; ++kc) {
        float v[8];
        #pragma unroll
        for (int i = 0; i < 8; ++i) v[i] = in[(size_t)(kc * 16 + hi * 8 + i) * HW2 + p];
        U8x pk;
        #pragma unroll
        for (int j = 0; j < 4; ++j) pk.u[j] = cvtpk(v[2 * j], v[2 * j + 1]);
        bfr[kc] = pk.v;
    }

    if (side == 0) {
        const float SCL = 0.18033688011112043f;   // log2(e)/8
        const int oct = sel;
        f32x16 acc;
        #pragma unroll
        for (int r = 0; r < 16; ++r)
            acc[r] = ipb[oct * 32 + (r & 3) + 8 * (r >> 2) + 4 * hi] * SCL;
        #pragma unroll
        for (int kc = 0; kc < 4; ++kc) {
            const float* wr = ipw + (size_t)(oct * 32 + q) * 64 + kc * 16 + hi * 8;
            U8x a;
            #pragma unroll
            for (int j = 0; j < 4; ++j) a.u[j] = cvtpk(wr[2 * j] * SCL, wr[2 * j + 1] * SCL);
            acc = MF32(a.v, bfr[kc], acc);
        }
        #pragma unroll
        for (int rp = 0; rp < 8; ++rp) {
            int j = (rp & 1) + ((rp >> 1) << 2) + 2 * hi + (oct << 4);
            Tt[tile * 32 + q][j] = cvtpk(acc[2 * rp], acc[2 * rp + 1]);
        }
    } else if (sel == 0) {
        #pragma unroll
        for (int oct = 0; oct < 2; ++oct) {
            f32x16 acc;
            #pragma unroll
            for (int r = 0; r < 16; ++r)
                acc[r] = ipb[64 + oct * 32 + (r & 3) + 8 * (r >> 2) + 4 * hi];
            #pragma unroll
            for (int kc = 0; kc < 4; ++kc) {
                const float* wr = ipw + (size_t)(64 + oct * 32 + q) * 64 + kc * 16 + hi * 8;
                U8x a;
                #pragma unroll
                for (int j = 0; j < 4; ++j) a.u[j] = cvtpk(wr[2 * j], wr[2 * j + 1]);
                acc = MF32(a.v, bfr[kc], acc);
            }
            #pragma unroll
            for (int rp = 0; rp < 8; ++rp) {
                int j = (rp & 1) + ((rp >> 1) << 2) + 2 * hi + (oct << 4);
                Tt[tile * 32 + q][j] = cvtpk(acc[2 * rp], acc[2 * rp + 1]);
            }
        }
    } else {
        // V: transposed + token-permuted scattered stores; plus mask
        int sub = (q >> 2) & 7;
        int pq = (((sub ^ (sub >> 1)) & 1) ? (q ^ 12) : q);
        u16_t* vb = Vt + (size_t)win * 64 * NTOK + n0 + tile * 32 + pq;
        #pragma unroll
        for (int oct = 0; oct < 2; ++oct) {
            f32x16 acc;
            #pragma unroll
            for (int r = 0; r < 16; ++r)
                acc[r] = ipb[128 + oct * 32 + (r & 3) + 8 * (r >> 2) + 4 * hi];
            #pragma unroll
            for (int kc = 0; kc < 4; ++kc) {
                const float* wr = ipw + (size_t)(128 + oct * 32 + q) * 64 + kc * 16 + hi * 8;
                U8x a;
                #pragma unroll
                for (int j = 0; j < 4; ++j) a.u[j] = cvtpk(wr[2 * j], wr[2 * j + 1]);
                acc = MF32(a.v, bfr[kc], acc);
            }
            #pragma unroll
            for (int r = 0; r < 16; ++r) {
                int ch = oct * 32 + (r & 3) + 8 * (r >> 2) + 4 * hi;
                vb[(size_t)ch * NTOK] = (u16_t)(cvtpk(acc[r], 0.f) & 0xffffu);
            }
        }
        if (hi == 0) Uf[tokb + tile * 32 + q] = (unc[p] > 0.01f) ? 0.f : -100.f;
    }
    __syncthreads();

    // coalesced store of Tt -> Q or K  ([tok][64] bf16)
    {
        u16_t* dst = side ? K : Q;
        int tok = threadIdx.x >> 2, s8 = (threadIdx.x & 3) * 8;
        u32_t v0[4], v1[4];
        #pragma unroll
        for (int j = 0; j < 4; ++j) { v0[j] = Tt[tok][s8 + j]; v1[j] = Tt[tok][s8 + 4 + j]; }
        u32_t* d = (u32_t*)(dst + (size_t)(tokb + tok) * 64) + s8;
        *(uint4*)d       = uint4{v0[0], v0[1], v0[2], v0[3]};
        *(uint4*)(d + 4) = uint4{v1[0], v1[1], v1[2], v1[3]};
    }
}

// ---- prep + meanV: b0 = fold out_proj*w1; b1..36 = conv weight pack; b37..100 = meanV from Vt ----
__global__ __launch_bounds__(256) void prepmv_kernel(
    const float* __restrict__ wop, const float* __restrict__ bop,
    const float* __restrict__ w1, const float* __restrict__ b1,
    const float* __restrict__ w3, const u16_t* __restrict__ Vt,
    float* __restrict__ Wc, float* __restrict__ bc, u16_t* __restrict__ Wpk,
    float* __restrict__ meanV)
{
    __shared__ float red[16][17];
    int tid = threadIdx.x;
    if (blockIdx.x == 0) {
        for (int idx = tid; idx < 4096; idx += 256) {
            int f = idx >> 6, d = idx & 63;
            float a = 0.f;
            for (int e = 0; e < 64; ++e) a += w1[f * 64 + e] * wop[e * 64 + d];
            Wc[idx] = a;
        }
        if (tid < 64) {
            float a = b1[tid];
            for (int e = 0; e < 64; ++e) a += w1[tid * 64 + e] * bop[e];
            bc[tid] = a;
        }
    } else if (blockIdx.x < 37) {
        for (int idx = (blockIdx.x - 1) * 256 + tid; idx < 36864; idx += 9216) {
            int i = idx & 7;
            int lane = (idx >> 3) & 63;
            int t2 = idx >> 9;
            int ks = t2 % 18, mf = t2 / 18;
            int oc = mf * 16 + (lane & 15);
            int g = lane >> 4;
            int tap = ks >> 1, icc = ks & 1;
            int dy = tap / 3, dx = tap - (tap / 3) * 3;
            int ic = icc * 32 + g * 8 + i;
            Wpk[idx] = (u16_t)(cvtpk(w3[(size_t)(oc * 64 + ic) * 9 + dy * 3 + dx], 0.f) & 0xffffu);
        }
    } else {
        int m = blockIdx.x - 37;
        int win = m >> 2, cq = m & 3;
        int chl = tid >> 4, seg = tid & 15;
        const uint2* src = (const uint2*)(Vt + (size_t)win * 64 * NTOK + (size_t)(cq * 16 + chl) * NTOK + seg * 144);
        float s = 0.f;
        for (int i = 0; i < 36; ++i) {      // 36 uint2 = 144 tokens per segment
            uint2 v = src[i];
            s += bflo(v.x) + bfhi(v.x) + bflo(v.y) + bfhi(v.y);
        }
        red[chl][seg] = s;
        __syncthreads();
        if (tid < 16) {
            float a = 0.f;
            #pragma unroll
            for (int k = 0; k < 16; ++k) a += red[tid][k];
            meanV[win * 64 + cq * 16 + tid] = a * (1.f / 2304.f);
        }
    }
}

// ---- attention: 32 q-rows/block, split-K x4, 1152 blocks; mask as MFMA-C bias ----
// launch_bounds (256,2): VGPR cap 256 — the allocator lands ~100-128 naturally, giving
// 4 blocks/CU at runtime. (256,4) forced a 64-VGPR cap -> per-iter accumulator spills
// (WRITE_SIZE 332 MB scratch, 206 us). Do NOT tighten the cap.
__global__ __launch_bounds__(256, 2) void attn_kernel(
    const u16_t* __restrict__ Q, const u16_t* __restrict__ K, const u16_t* __restrict__ Vt,
    const float* __restrict__ Uf, const float* __restrict__ meanV, u16_t* __restrict__ Oatt)
{
    __shared__ float Ored[4][32][68];
    __shared__ float Lred[4][32];

    const int bid = (blockIdx.x & 7) * 144 + (blockIdx.x >> 3);   // XCD-bijective (1152%8==0)
    const int lane = threadIdx.x & 63;
    const int kq = threadIdx.x >> 6;
    const int q  = lane & 31;
    const int hi = lane >> 5;
    const int win = bid / 72;
    const int rg  = bid % 72;
    const int row0 = rg * 32;

    const u16_t* Qw = Q + (size_t)win * NTOK * 64;
    const u16_t* Kw = K + (size_t)win * NTOK * 64;
    const u16_t* Vw = Vt + (size_t)win * 64 * NTOK;
    const float* Uw = Uf + win * NTOK;

    bf16x8 qb[4];
    #pragma unroll
    for (int s = 0; s < 4; ++s)
        qb[s] = *(const bf16x8*)(Qw + (size_t)(row0 + q) * 64 + s * 16 + hi * 8);

    const f32x16 Z16 = {0.f,0.f,0.f,0.f,0.f,0.f,0.f,0.f,0.f,0.f,0.f,0.f,0.f,0.f,0.f,0.f};
    f32x16 acc0 = Z16, acc1 = Z16;
    float lsum = 0.f;

    const u16_t* kp = Kw + (size_t)(kq * 576 + q) * 64 + hi * 8;
    const u16_t* vp = Vw + (size_t)q * NTOK + kq * 576 + hi * 8;
    const float* up = Uw + kq * 576 + 4 * hi;

    bf16x8 kA0,kA1,kA2,kA3, vA0,vA1,vA2,vA3;
    bf16x8 kB0,kB1,kB2,kB3, vB0,vB1,vB2,vB3;
    F16x bA, bB;

#define LDSET(sfx, CT) { \
    const u16_t* _k = kp + (size_t)(CT) * 2048; \
    k##sfx##0 = *(const bf16x8*)(_k);      k##sfx##1 = *(const bf16x8*)(_k + 16); \
    k##sfx##2 = *(const bf16x8*)(_k + 32); k##sfx##3 = *(const bf16x8*)(_k + 48); \
    const u16_t* _v = vp + (CT) * 32; \
    v##sfx##0 = *(const bf16x8*)(_v);             v##sfx##1 = *(const bf16x8*)(_v + 16); \
    v##sfx##2 = *(const bf16x8*)(_v + 32 * NTOK); v##sfx##3 = *(const bf16x8*)(_v + 32 * NTOK + 16); \
    const float* _u = up + (CT) * 32; \
    b##sfx.f4[0] = *(const float4*)(_u);      b##sfx.f4[1] = *(const float4*)(_u + 8); \
    b##sfx.f4[2] = *(const float4*)(_u + 16); b##sfx.f4[3] = *(const float4*)(_u + 24); }

#define QS_TILE(sfx) { \
    f32x16 s = b##sfx.v; \
    s = MF32(k##sfx##0, qb[0], s); s = MF32(k##sfx##1, qb[1], s); \
    s = MF32(k##sfx##2, qb[2], s); s = MF32(k##sfx##3, qb[3], s); \
    float pv[16]; float lls = 0.f; \
    _Pragma("unroll") for (int r = 0; r < 16; ++r) { pv[r] = __builtin_exp2f(s[r]); lls += pv[r]; } \
    lsum += lls; \
    U8x f0, f1; \
    _Pragma("unroll") for (int j = 0; j < 4; ++j) { \
        f0.u[j] = cvtpk(pv[2 * j], pv[2 * j + 1]); \
        f1.u[j] = cvtpk(pv[8 + 2 * j], pv[8 + 2 * j + 1]); } \
    acc0 = MF32(v##sfx##0, f0.v, acc0); acc0 = MF32(v##sfx##1, f1.v, acc0); \
    acc1 = MF32(v##sfx##2, f0.v, acc1); acc1 = MF32(v##sfx##3, f1.v, acc1); }

    LDSET(A, 0)
    #pragma unroll 1
    for (int tt = 0; tt < 9; ++tt) {
        LDSET(B, 2 * tt + 1)
        QS_TILE(A)
        if (tt < 8) LDSET(A, 2 * tt + 2)
        QS_TILE(B)
    }
#undef QS_TILE
#undef LDSET

    lsum += __shfl_xor(lsum, 32);
    if (hi == 0) Lred[kq][q] = lsum;

    #pragma unroll
    for (int rr = 0; rr < 4; ++rr) {
        float4 v0 = { acc0[4*rr], acc0[4*rr+1], acc0[4*rr+2], acc0[4*rr+3] };
        float4 v1 = { acc1[4*rr], acc1[4*rr+1], acc1[4*rr+2], acc1[4*rr+3] };
        *(float4*)&Ored[kq][q][8 * rr + 4 * hi]      = v0;
        *(float4*)&Ored[kq][q][32 + 8 * rr + 4 * hi] = v1;
    }
    __syncthreads();

    const int qr = threadIdx.x >> 3;
    const int ch0 = (threadIdx.x & 7) * 8;
    float o[8] = {0.f,0.f,0.f,0.f,0.f,0.f,0.f,0.f};
    #pragma unroll
    for (int w = 0; w < 4; ++w) {
        float4 a = *(float4*)&Ored[w][qr][ch0];
        float4 b = *(float4*)&Ored[w][qr][ch0 + 4];
        o[0] += a.x; o[1] += a.y; o[2] += a.z; o[3] += a.w;
        o[4] += b.x; o[5] += b.y; o[6] += b.z; o[7] += b.w;
    }
    float l = Lred[0][qr] + Lred[1][qr] + Lred[2][qr] + Lred[3][qr];
    float linv = (l > 0.f) ? 1.f / l : 0.f;
    int row = row0 + qr;
    uint4 wv;
    if (Uw[row] == 0.f) {   // uncertain row
        wv = uint4{ cvtpk(o[0]*linv, o[1]*linv), cvtpk(o[2]*linv, o[3]*linv),
                    cvtpk(o[4]*linv, o[5]*linv), cvtpk(o[6]*linv, o[7]*linv) };
    } else {
        const float* mv = meanV + win * 64 + ch0;
        wv = uint4{ cvtpk(mv[0], mv[1]), cvtpk(mv[2], mv[3]),
                    cvtpk(mv[4], mv[5]), cvtpk(mv[6], mv[7]) };
    }
    *(uint4*)(Oatt + (size_t)(win * NTOK + row) * 64 + ch0) = wv;
}

// ---- refined (bf16 NHWC [p][64]) = x + Oatt @ Wc^T + bc  — MFMA GEMM ----
__global__ __launch_bounds__(256) void refined_kernel(
    const float* __restrict__ x, const u16_t* __restrict__ Oatt,
    const float* __restrict__ Wc, const float* __restrict__ bc,
    u16_t* __restrict__ refd)
{
    __shared__ u32_t Tt[64][33];
    const int bid = (blockIdx.x & 7) * 72 + (blockIdx.x >> 3);   // 576 blocks
    const int tokb = bid * 64;
    const int win = tokb / NTOK;
    const int n0 = tokb - win * NTOK;

    const int w = threadIdx.x >> 6;
    const int lane = threadIdx.x & 63;
    const int tile = w & 1;
    const int oct = w >> 1;
    const int q = lane & 31;
    const int hi = lane >> 5;

    int n = n0 + tile * 32 + q;
    int p = ((win >> 2) * 48 + n / 48) * 192 + (win & 3) * 48 + n % 48;

    const u16_t* ob = Oatt + (size_t)(tokb + tile * 32 + q) * 64 + hi * 8;
    bf16x8 bfr[4];
    #pragma unroll
    for (int kc = 0; kc < 4; ++kc) bfr[kc] = *(const bf16x8*)(ob + kc * 16);

    f32x16 acc;
    #pragma unroll
    for (int r = 0; r < 16; ++r)
        acc[r] = bc[oct * 32 + (r & 3) + 8 * (r >> 2) + 4 * hi];
    #pragma unroll
    for (int kc = 0; kc < 4; ++kc) {
        const float* wr = Wc + (size_t)(oct * 32 + q) * 64 + kc * 16 + hi * 8;
        U8x a;
        #pragma unroll
        for (int j = 0; j < 4; ++j) a.u[j] = cvtpk(wr[2 * j], wr[2 * j + 1]);
        acc = MF32(a.v, bfr[kc], acc);
    }
    #pragma unroll
    for (int rp = 0; rp < 8; ++rp) {
        int ch = oct * 32 + (2 * rp & 3) + 8 * (rp >> 1) + 4 * hi;
        float xa = x[(size_t)ch * HW2 + p] + acc[2 * rp];
        float xb = x[(size_t)(ch + 1) * HW2 + p] + acc[2 * rp + 1];
        int j = (rp & 1) + ((rp >> 1) << 2) + 2 * hi + (oct << 4);
        Tt[tile * 32 + q][j] = cvtpk(xa, xb);
    }
    __syncthreads();

    {
        int tok = threadIdx.x >> 2, s8 = (threadIdx.x & 3) * 8;
        int nn = n0 + tok;
        int pp = ((win >> 2) * 48 + nn / 48) * 192 + (win & 3) * 48 + nn % 48;
        u32_t v0[4], v1[4];
        #pragma unroll
        for (int j = 0; j < 4; ++j) { v0[j] = Tt[tok][s8 + j]; v1[j] = Tt[tok][s8 + 4 + j]; }
        u32_t* d = (u32_t*)(refd + (size_t)pp * 64) + s8;
        *(uint4*)d       = uint4{v0[0], v0[1], v0[2], v0[3]};
        *(uint4*)(d + 4) = uint4{v1[0], v1[1], v1[2], v1[3]};
    }
}

// ------- conv3x3(+bias,relu)->out0, 1x1->out1, partition map; implicit-GEMM MFMA, NHWC in -------
__global__ __launch_bounds__(256) void conv_kernel(
    const u16_t* __restrict__ refined, const u16_t* __restrict__ Wpk,
    const float* __restrict__ b3, const float* __restrict__ w4, const float* __restrict__ b4,
    float* __restrict__ out0, float* __restrict__ out1, float* __restrict__ pm)
{
    __shared__ u16_t tile[3 * 50 * 64];    // [pix][ic], slot-swizzled; 19,200 B
    __shared__ float ps[48];
    int bid = (blockIdx.x & 7) * 96 + (blockIdx.x >> 3);
    const int y  = bid >> 2;
    const int x0 = (bid & 3) * 48;
    const int tid = threadIdx.x;
    if (tid < 48) ps[tid] = 0.f;

    for (int idx = tid; idx < 1200; idx += 256) {     // 150 pixels x 8 chunks
        int tg = idx & 7;
        int pix = idx >> 3;
        int r = pix / 50, cc = pix - r * 50;
        int yy = y - 1 + r, xg = x0 - 1 + cc;
        bf16x8 val = {0,0,0,0,0,0,0,0};
        if ((unsigned)yy < 192u && (unsigned)xg < 192u)
            val = *(const bf16x8*)(refined + ((size_t)(yy * 192 + xg)) * 64 + tg * 8);
        int slot = (tg + cc) & 7;
        *(bf16x8*)((char*)tile + (size_t)pix * 128 + slot * 16) = val;
    }
    __syncthreads();

    const int lane = tid & 63, mf = tid >> 6;
    const int ln = lane & 15, g = lane >> 4;

    bf16x8 wf[18];
    #pragma unroll
    for (int ks = 0; ks < 18; ++ks)
        wf[ks] = *(const bf16x8*)(Wpk + (size_t)((mf * 18 + ks) * 64 + lane) * 8);

    float b3v[4], w4v[4];
    #pragma unroll
    for (int r = 0; r < 4; ++r) { int oc = mf * 16 + 4 * g + r; b3v[r] = b3[oc]; w4v[r] = w4[oc]; }

    for (int nf = 0; nf < 3; ++nf) {
        int xl = nf * 16 + ln;
        f32x4 acc0 = {0.f,0.f,0.f,0.f}, acc1 = acc0;
        #pragma unroll
        for (int ks = 0; ks < 18; ++ks) {
            int tap = ks >> 1, icc = ks & 1;
            int dy = tap / 3, dx = tap - (tap / 3) * 3;
            int cc = xl + dx;
            int slot = (icc * 4 + g + cc) & 7;
            bf16x8 bfr = *(const bf16x8*)((const char*)tile + (size_t)(dy * 50 + cc) * 128 + slot * 16);
            if (ks & 1) acc1 = __builtin_amdgcn_mfma_f32_16x16x32_bf16(wf[ks], bfr, acc1, 0, 0, 0);
            else        acc0 = __builtin_amdgcn_mfma_f32_16x16x32_bf16(wf[ks], bfr, acc0, 0, 0, 0);
        }
        int xg = x0 + xl;
        float s4 = 0.f;
        #pragma unroll
        for (int r = 0; r < 4; ++r) {
            int oc = mf * 16 + 4 * g + r;
            float v = fmaxf(acc0[r] + acc1[r] + b3v[r], 0.f);
            out0[(size_t)oc * HW2 + y * 192 + xg] = v;
            s4 += v * w4v[r];
        }
        atomicAdd(&ps[xl], s4);
    }
    __syncthreads();
    if (tid < 48) {
        int xg = x0 + tid;
        out1[y * 192 + xg] = ps[tid] + b4[0];
        int ym = y % 48, xm = xg % 48;
        pm[y * 192 + xg] = ((ym == 0) | (ym == 47) | (xm == 0) | (xm == 47)) ? 0.6f : 1.0f;
    }
}

extern "C" void kernel_launch(void* const* d_in, const int* in_sizes, int n_in,
                              void* d_out, int out_size, void* d_ws, size_t ws_size,
                              hipStream_t stream)
{
    const float* x   = (const float*)d_in[0];
    const float* ref = (const float*)d_in[1];
    const float* unc = (const float*)d_in[2];
    const float* ipw = (const float*)d_in[3];
    const float* ipb = (const float*)d_in[4];
    const float* opw = (const float*)d_in[5];
    const float* opb = (const float*)d_in[6];
    const float* w1  = (const float*)d_in[7];
    const float* b1  = (const float*)d_in[8];
    const float* w3  = (const float*)d_in[9];
    const float* b3  = (const float*)d_in[10];
    const float* w4  = (const float*)d_in[11];
    const float* b4  = (const float*)d_in[12];

    char* ws = (char*)d_ws;
    u16_t* Qb    = (u16_t*)(ws);                  // 4,718,592
    u16_t* Kb    = (u16_t*)(ws + 4718592);        // 4,718,592
    u16_t* Vtb   = (u16_t*)(ws + 9437184);        // 4,718,592
    float* Ufp   = (float*)(ws + 14155776);       // 147,456
    float* meanV = (float*)(ws + 14303232);       // 4,096
    float* Wc    = (float*)(ws + 14307328);       // 16,384
    float* bc    = (float*)(ws + 14323712);       // 256
    u16_t* Wpk   = (u16_t*)(ws + 14323968);       // 73,728
    u16_t* Oatt  = (u16_t*)(ws + 14397696);       // 4,718,592
    u16_t* refd  = (u16_t*)(ws + 19116288);       // 4,718,592  (total 23,834,880 B)

    float* out0 = (float*)d_out;                  // r3: [1,64,192,192]
    float* out1 = out0 + 2359296;                 // out: [1,1,192,192]
    float* pmap = out0 + 2396160;                 // partition_map

    proj_kernel   <<<1152, 256, 0, stream>>>(x, ref, unc, ipw, ipb, Qb, Kb, Vtb, Ufp);
    prepmv_kernel <<<101,  256, 0, stream>>>(opw, opb, w1, b1, w3, Vtb, Wc, bc, Wpk, meanV);
    attn_kernel   <<<1152, 256, 0, stream>>>(Qb, Kb, Vtb, Ufp, meanV, Oatt);
    refined_kernel<<<576,  256, 0, stream>>>(x, Oatt, Wc, bc, refd);
    conv_kernel   <<<768,  256, 0, stream>>>(refd, Wpk, b3, w4, b4, out0, out1, pmap);
}

// Round 10
// 207.202 us; speedup vs baseline: 1.6522x; 1.1611x over previous
//
#include <hip/hip_runtime.h>
#include <hip/hip_bf16.h>

typedef unsigned char  u8_t;
typedef unsigned short u16_t;
typedef unsigned int   u32_t;
typedef __attribute__((ext_vector_type(8))) short bf16x8;
typedef __attribute__((ext_vector_type(4))) float f32x4;
typedef __attribute__((ext_vector_type(16))) float f32x16;

#define HW2  36864   // 192*192
#define NTOK 2304    // tokens per 48x48 window

__device__ __forceinline__ u32_t cvtpk(float a, float b) {
    union { __hip_bfloat162 h; u32_t u; } c;
    c.h = __float22bfloat162_rn(float2{a, b});
    return c.u;
}
__device__ __forceinline__ float bfhi(u32_t u) { union { u32_t u; float f; } c; c.u = u & 0xffff0000u; return c.f; }
__device__ __forceinline__ float bflo(u32_t u) { union { u32_t u; float f; } c; c.u = u << 16; return c.f; }

union U8x { u32_t u[4]; bf16x8 v; };
union F16x { float4 f4[4]; f32x16 v; };

#define MF32(A, B, C) __builtin_amdgcn_mfma_f32_32x32x16_bf16(A, B, C, 0, 0, 0)

// ---- MFMA projections: even blocks = Q from x; odd blocks = K,V,mask from ref ----
__global__ __launch_bounds__(256) void proj_kernel(
    const float* __restrict__ x, const float* __restrict__ ref, const float* __restrict__ unc,
    const float* __restrict__ ipw, const float* __restrict__ ipb,
    u16_t* __restrict__ Q, u16_t* __restrict__ K, u16_t* __restrict__ Vt, float* __restrict__ Uf)
{
    __shared__ u32_t Tt[64][33];
    const int side = blockIdx.x & 1;             // 0: Q,  1: K/V
    const int hb = blockIdx.x >> 1;              // 0..575
    const int bid = (hb & 7) * 72 + (hb >> 3);   // XCD-bijective (576%8==0)
    const int tokb = bid * 64;
    const int win = tokb / NTOK;
    const int n0 = tokb - win * NTOK;

    const int w = threadIdx.x >> 6;
    const int lane = threadIdx.x & 63;
    const int tile = w & 1;
    const int sel = w >> 1;                      // Q: octile; KV: 0=K 1=V
    const int q = lane & 31;
    const int hi = lane >> 5;

    const float* in = side ? ref : x;
    int n = n0 + tile * 32 + q;
    int p = ((win >> 2) * 48 + n / 48) * 192 + (win & 3) * 48 + n % 48;

    bf16x8 bfr[4];
    #pragma unroll
    for (int kc = 0; kc < 4; ++kc) {
        float v[8];
        #pragma unroll
        for (int i = 0; i < 8; ++i) v[i] = in[(size_t)(kc * 16 + hi * 8 + i) * HW2 + p];
        U8x pk;
        #pragma unroll
        for (int j = 0; j < 4; ++j) pk.u[j] = cvtpk(v[2 * j], v[2 * j + 1]);
        bfr[kc] = pk.v;
    }

    if (side == 0) {
        const float SCL = 0.18033688011112043f;   // log2(e)/8
        const int oct = sel;
        f32x16 acc;
        #pragma unroll
        for (int r = 0; r < 16; ++r)
            acc[r] = ipb[oct * 32 + (r & 3) + 8 * (r >> 2) + 4 * hi] * SCL;
        #pragma unroll
        for (int kc = 0; kc < 4; ++kc) {
            const float* wr = ipw + (size_t)(oct * 32 + q) * 64 + kc * 16 + hi * 8;
            U8x a;
            #pragma unroll
            for (int j = 0; j < 4; ++j) a.u[j] = cvtpk(wr[2 * j] * SCL, wr[2 * j + 1] * SCL);
            acc = MF32(a.v, bfr[kc], acc);
        }
        #pragma unroll
        for (int rp = 0; rp < 8; ++rp) {
            int j = (rp & 1) + ((rp >> 1) << 2) + 2 * hi + (oct << 4);
            Tt[tile * 32 + q][j] = cvtpk(acc[2 * rp], acc[2 * rp + 1]);
        }
    } else if (sel == 0) {
        #pragma unroll
        for (int oct = 0; oct < 2; ++oct) {
            f32x16 acc;
            #pragma unroll
            for (int r = 0; r < 16; ++r)
                acc[r] = ipb[64 + oct * 32 + (r & 3) + 8 * (r >> 2) + 4 * hi];
            #pragma unroll
            for (int kc = 0; kc < 4; ++kc) {
                const float* wr = ipw + (size_t)(64 + oct * 32 + q) * 64 + kc * 16 + hi * 8;
                U8x a;
                #pragma unroll
                for (int j = 0; j < 4; ++j) a.u[j] = cvtpk(wr[2 * j], wr[2 * j + 1]);
                acc = MF32(a.v, bfr[kc], acc);
            }
            #pragma unroll
            for (int rp = 0; rp < 8; ++rp) {
                int j = (rp & 1) + ((rp >> 1) << 2) + 2 * hi + (oct << 4);
                Tt[tile * 32 + q][j] = cvtpk(acc[2 * rp], acc[2 * rp + 1]);
            }
        }
    } else {
        // V: transposed + token-permuted scattered stores; plus mask
        int sub = (q >> 2) & 7;
        int pq = (((sub ^ (sub >> 1)) & 1) ? (q ^ 12) : q);
        u16_t* vb = Vt + (size_t)win * 64 * NTOK + n0 + tile * 32 + pq;
        #pragma unroll
        for (int oct = 0; oct < 2; ++oct) {
            f32x16 acc;
            #pragma unroll
            for (int r = 0; r < 16; ++r)
                acc[r] = ipb[128 + oct * 32 + (r & 3) + 8 * (r >> 2) + 4 * hi];
            #pragma unroll
            for (int kc = 0; kc < 4; ++kc) {
                const float* wr = ipw + (size_t)(128 + oct * 32 + q) * 64 + kc * 16 + hi * 8;
                U8x a;
                #pragma unroll
                for (int j = 0; j < 4; ++j) a.u[j] = cvtpk(wr[2 * j], wr[2 * j + 1]);
                acc = MF32(a.v, bfr[kc], acc);
            }
            #pragma unroll
            for (int r = 0; r < 16; ++r) {
                int ch = oct * 32 + (r & 3) + 8 * (r >> 2) + 4 * hi;
                vb[(size_t)ch * NTOK] = (u16_t)(cvtpk(acc[r], 0.f) & 0xffffu);
            }
        }
        if (hi == 0) Uf[tokb + tile * 32 + q] = (unc[p] > 0.01f) ? 0.f : -100.f;
    }
    __syncthreads();

    // coalesced store of Tt -> Q or K  ([tok][64] bf16)
    {
        u16_t* dst = side ? K : Q;
        int tok = threadIdx.x >> 2, s8 = (threadIdx.x & 3) * 8;
        u32_t v0[4], v1[4];
        #pragma unroll
        for (int j = 0; j < 4; ++j) { v0[j] = Tt[tok][s8 + j]; v1[j] = Tt[tok][s8 + 4 + j]; }
        u32_t* d = (u32_t*)(dst + (size_t)(tokb + tok) * 64) + s8;
        *(uint4*)d       = uint4{v0[0], v0[1], v0[2], v0[3]};
        *(uint4*)(d + 4) = uint4{v1[0], v1[1], v1[2], v1[3]};
    }
}

// ---- prep + meanV: b0 = fold out_proj*w1; b1..36 = conv weight pack; b37..100 = meanV from Vt ----
__global__ __launch_bounds__(256) void prepmv_kernel(
    const float* __restrict__ wop, const float* __restrict__ bop,
    const float* __restrict__ w1, const float* __restrict__ b1,
    const float* __restrict__ w3, const u16_t* __restrict__ Vt,
    float* __restrict__ Wc, float* __restrict__ bc, u16_t* __restrict__ Wpk,
    float* __restrict__ meanV)
{
    __shared__ float red[16][17];
    int tid = threadIdx.x;
    if (blockIdx.x == 0) {
        for (int idx = tid; idx < 4096; idx += 256) {
            int f = idx >> 6, d = idx & 63;
            float a = 0.f;
            for (int e = 0; e < 64; ++e) a += w1[f * 64 + e] * wop[e * 64 + d];
            Wc[idx] = a;
        }
        if (tid < 64) {
            float a = b1[tid];
            for (int e = 0; e < 64; ++e) a += w1[tid * 64 + e] * bop[e];
            bc[tid] = a;
        }
    } else if (blockIdx.x < 37) {
        for (int idx = (blockIdx.x - 1) * 256 + tid; idx < 36864; idx += 9216) {
            int i = idx & 7;
            int lane = (idx >> 3) & 63;
            int t2 = idx >> 9;
            int ks = t2 % 18, mf = t2 / 18;
            int oc = mf * 16 + (lane & 15);
            int g = lane >> 4;
            int tap = ks >> 1, icc = ks & 1;
            int dy = tap / 3, dx = tap - (tap / 3) * 3;
            int ic = icc * 32 + g * 8 + i;
            Wpk[idx] = (u16_t)(cvtpk(w3[(size_t)(oc * 64 + ic) * 9 + dy * 3 + dx], 0.f) & 0xffffu);
        }
    } else {
        int m = blockIdx.x - 37;
        int win = m >> 2, cq = m & 3;
        int chl = tid >> 4, seg = tid & 15;
        const uint2* src = (const uint2*)(Vt + (size_t)win * 64 * NTOK + (size_t)(cq * 16 + chl) * NTOK + seg * 144);
        float s = 0.f;
        for (int i = 0; i < 36; ++i) {      // 36 uint2 = 144 tokens per segment
            uint2 v = src[i];
            s += bflo(v.x) + bfhi(v.x) + bflo(v.y) + bfhi(v.y);
        }
        red[chl][seg] = s;
        __syncthreads();
        if (tid < 16) {
            float a = 0.f;
            #pragma unroll
            for (int k = 0; k < 16; ++k) a += red[tid][k];
            meanV[win * 64 + cq * 16 + tid] = a * (1.f / 2304.f);
        }
    }
}

// ---- attention: 64 q-rows/block (dual-tile body = long latency cover), block-level
// split-K x2 (1152 blocks) + in-block split-K x4. Writes RAW bf16 partial O + f32 row-sums;
// normalize + certain-row meanV override folded into refined_kernel.
// launch_bounds (256,2): do NOT tighten — (256,4) forced 64-VGPR cap -> spills (r8: 332MB scratch).
__global__ __launch_bounds__(256, 2) void attn_kernel(
    const u16_t* __restrict__ Q, const u16_t* __restrict__ K, const u16_t* __restrict__ Vt,
    const float* __restrict__ Uf, u16_t* __restrict__ Opart, float* __restrict__ Lpart)
{
    __shared__ float Ored[4][32][68];
    __shared__ float Lred2[2][4][32];

    const int bid = (blockIdx.x & 7) * 144 + (blockIdx.x >> 3);   // XCD-bijective (1152%8==0)
    const int lane = threadIdx.x & 63;
    const int kq = threadIdx.x >> 6;
    const int q  = lane & 31;
    const int hi = lane >> 5;
    const int win = bid / 72;
    const int rem = bid % 72;
    const int rg   = rem >> 1;       // 36 row-groups of 64
    const int half = rem & 1;        // K-half: cols [half*1152, half*1152+1152)
    const int row0 = rg * 64;

    const u16_t* Qw = Q + (size_t)win * NTOK * 64;
    const u16_t* Kw = K + (size_t)win * NTOK * 64;
    const u16_t* Vw = Vt + (size_t)win * 64 * NTOK;
    const float* Uw = Uf + win * NTOK;

    bf16x8 qb0[4], qb1[4];
    #pragma unroll
    for (int s = 0; s < 4; ++s) {
        qb0[s] = *(const bf16x8*)(Qw + (size_t)(row0 + q) * 64 + s * 16 + hi * 8);
        qb1[s] = *(const bf16x8*)(Qw + (size_t)(row0 + 32 + q) * 64 + s * 16 + hi * 8);
    }

    const f32x16 Z16 = {0.f,0.f,0.f,0.f,0.f,0.f,0.f,0.f,0.f,0.f,0.f,0.f,0.f,0.f,0.f,0.f};
    f32x16 acc00 = Z16, acc01 = Z16, acc10 = Z16, acc11 = Z16;
    float lsum0 = 0.f, lsum1 = 0.f;

    const int cbase = half * 1152 + kq * 288;    // 9 tiles of 32 cols per wave
    const u16_t* kp = Kw + (size_t)(cbase + q) * 64 + hi * 8;
    const u16_t* vp = Vw + (size_t)q * NTOK + cbase + hi * 8;
    const float* up = Uw + cbase + 4 * hi;

    bf16x8 kA0,kA1,kA2,kA3, vA0,vA1,vA2,vA3;
    bf16x8 kB0,kB1,kB2,kB3, vB0,vB1,vB2,vB3;
    F16x bA, bB;

#define LDSET(sfx, CT) { \
    const u16_t* _k = kp + (size_t)(CT) * 2048; \
    k##sfx##0 = *(const bf16x8*)(_k);      k##sfx##1 = *(const bf16x8*)(_k + 16); \
    k##sfx##2 = *(const bf16x8*)(_k + 32); k##sfx##3 = *(const bf16x8*)(_k + 48); \
    const u16_t* _v = vp + (CT) * 32; \
    v##sfx##0 = *(const bf16x8*)(_v);             v##sfx##1 = *(const bf16x8*)(_v + 16); \
    v##sfx##2 = *(const bf16x8*)(_v + 32 * NTOK); v##sfx##3 = *(const bf16x8*)(_v + 32 * NTOK + 16); \
    const float* _u = up + (CT) * 32; \
    b##sfx.f4[0] = *(const float4*)(_u);      b##sfx.f4[1] = *(const float4*)(_u + 8); \
    b##sfx.f4[2] = *(const float4*)(_u + 16); b##sfx.f4[3] = *(const float4*)(_u + 24); }

#define QS_TILE(sfx, QB, ACC0, ACC1, LSUM) { \
    f32x16 s = b##sfx.v; \
    s = MF32(k##sfx##0, QB[0], s); s = MF32(k##sfx##1, QB[1], s); \
    s = MF32(k##sfx##2, QB[2], s); s = MF32(k##sfx##3, QB[3], s); \
    float pv[16]; float lls = 0.f; \
    _Pragma("unroll") for (int r = 0; r < 16; ++r) { pv[r] = __builtin_exp2f(s[r]); lls += pv[r]; } \
    LSUM += lls; \
    U8x f0, f1; \
    _Pragma("unroll") for (int j = 0; j < 4; ++j) { \
        f0.u[j] = cvtpk(pv[2 * j], pv[2 * j + 1]); \
        f1.u[j] = cvtpk(pv[8 + 2 * j], pv[8 + 2 * j + 1]); } \
    ACC0 = MF32(v##sfx##0, f0.v, ACC0); ACC0 = MF32(v##sfx##1, f1.v, ACC0); \
    ACC1 = MF32(v##sfx##2, f0.v, ACC1); ACC1 = MF32(v##sfx##3, f1.v, ACC1); }

#define BODY(sfx) { QS_TILE(sfx, qb0, acc00, acc01, lsum0) QS_TILE(sfx, qb1, acc10, acc11, lsum1) }

    LDSET(A, 0)
    #pragma unroll 1
    for (int tt = 0; tt < 4; ++tt) {
        LDSET(B, 2 * tt + 1)
        BODY(A)
        LDSET(A, 2 * tt + 2)
        BODY(B)
    }
    BODY(A)   // tile 8
#undef BODY
#undef QS_TILE
#undef LDSET

    float l0 = lsum0 + __shfl_xor(lsum0, 32);
    float l1 = lsum1 + __shfl_xor(lsum1, 32);
    if (hi == 0) { Lred2[0][kq][q] = l0; Lred2[1][kq][q] = l1; }

    const int qr = threadIdx.x >> 3;
    const int ch0 = (threadIdx.x & 7) * 8;
    u16_t* Op = Opart + (size_t)half * 2359296;   // 36864*64
    float* Lp = Lpart + half * 36864;

    #pragma unroll
    for (int qs = 0; qs < 2; ++qs) {
        f32x16 a0 = qs ? acc10 : acc00;
        f32x16 a1 = qs ? acc11 : acc01;
        #pragma unroll
        for (int rr = 0; rr < 4; ++rr) {
            float4 v0 = { a0[4*rr], a0[4*rr+1], a0[4*rr+2], a0[4*rr+3] };
            float4 v1 = { a1[4*rr], a1[4*rr+1], a1[4*rr+2], a1[4*rr+3] };
            *(float4*)&Ored[kq][q][8 * rr + 4 * hi]      = v0;
            *(float4*)&Ored[kq][q][32 + 8 * rr + 4 * hi] = v1;
        }
        __syncthreads();
        float o[8] = {0.f,0.f,0.f,0.f,0.f,0.f,0.f,0.f};
        #pragma unroll
        for (int w = 0; w < 4; ++w) {
            float4 a = *(float4*)&Ored[w][qr][ch0];
            float4 b = *(float4*)&Ored[w][qr][ch0 + 4];
            o[0] += a.x; o[1] += a.y; o[2] += a.z; o[3] += a.w;
            o[4] += b.x; o[5] += b.y; o[6] += b.z; o[7] += b.w;
        }
        int row = row0 + 32 * qs + qr;
        uint4 wv = uint4{ cvtpk(o[0], o[1]), cvtpk(o[2], o[3]),
                          cvtpk(o[4], o[5]), cvtpk(o[6], o[7]) };
        *(uint4*)(Op + (size_t)(win * NTOK + row) * 64 + ch0) = wv;
        if ((threadIdx.x & 7) == 0) {
            float l = Lred2[qs][0][qr] + Lred2[qs][1][qr] + Lred2[qs][2][qr] + Lred2[qs][3][qr];
            Lp[win * NTOK + row] = l;
        }
        __syncthreads();
    }
}

// ---- refined (bf16 NHWC [p][64]) = x + (merge(Opart)/l or meanV) @ Wc^T + bc ----
__global__ __launch_bounds__(256) void refined_kernel(
    const float* __restrict__ x, const u16_t* __restrict__ Opart, const float* __restrict__ Lpart,
    const float* __restrict__ Uf, const float* __restrict__ meanV,
    const float* __restrict__ Wc, const float* __restrict__ bc,
    u16_t* __restrict__ refd)
{
    __shared__ u32_t Tt[64][33];
    const int bid = (blockIdx.x & 7) * 72 + (blockIdx.x >> 3);   // 576 blocks
    const int tokb = bid * 64;
    const int win = tokb / NTOK;
    const int n0 = tokb - win * NTOK;

    const int w = threadIdx.x >> 6;
    const int lane = threadIdx.x & 63;
    const int tile = w & 1;
    const int oct = w >> 1;
    const int q = lane & 31;
    const int hi = lane >> 5;

    int n = n0 + tile * 32 + q;
    int p = ((win >> 2) * 48 + n / 48) * 192 + (win & 3) * 48 + n % 48;
    int t = tokb + tile * 32 + q;     // global token == win*NTOK + row in attn

    // merge the two K-half partials -> normalized bf16 B-frags (or meanV for certain rows)
    float l = Lpart[t] + Lpart[36864 + t];
    float linv = (l > 0.f) ? 1.f / l : 0.f;
    bool certain = (Uf[t] != 0.f);
    const u16_t* p0 = Opart + (size_t)t * 64 + hi * 8;
    const u16_t* p1 = p0 + 2359296;
    const float* mv = meanV + win * 64 + hi * 8;

    bf16x8 bfr[4];
    #pragma unroll
    for (int kc = 0; kc < 4; ++kc) {
        U8x ua, ub, uo;
        ua.v = *(const bf16x8*)(p0 + kc * 16);
        ub.v = *(const bf16x8*)(p1 + kc * 16);
        if (!certain) {
            #pragma unroll
            for (int j = 0; j < 4; ++j) {
                float s0 = (bflo(ua.u[j]) + bflo(ub.u[j])) * linv;
                float s1 = (bfhi(ua.u[j]) + bfhi(ub.u[j])) * linv;
                uo.u[j] = cvtpk(s0, s1);
            }
        } else {
            const float* m = mv + kc * 16;
            #pragma unroll
            for (int j = 0; j < 4; ++j) uo.u[j] = cvtpk(m[2 * j], m[2 * j + 1]);
        }
        bfr[kc] = uo.v;
    }

    f32x16 acc;
    #pragma unroll
    for (int r = 0; r < 16; ++r)
        acc[r] = bc[oct * 32 + (r & 3) + 8 * (r >> 2) + 4 * hi];
    #pragma unroll
    for (int kc = 0; kc < 4; ++kc) {
        const float* wr = Wc + (size_t)(oct * 32 + q) * 64 + kc * 16 + hi * 8;
        U8x a;
        #pragma unroll
        for (int j = 0; j < 4; ++j) a.u[j] = cvtpk(wr[2 * j], wr[2 * j + 1]);
        acc = MF32(a.v, bfr[kc], acc);
    }
    #pragma unroll
    for (int rp = 0; rp < 8; ++rp) {
        int ch = oct * 32 + (2 * rp & 3) + 8 * (rp >> 1) + 4 * hi;
        float xa = x[(size_t)ch * HW2 + p] + acc[2 * rp];
        float xb = x[(size_t)(ch + 1) * HW2 + p] + acc[2 * rp + 1];
        int j = (rp & 1) + ((rp >> 1) << 2) + 2 * hi + (oct << 4);
        Tt[tile * 32 + q][j] = cvtpk(xa, xb);
    }
    __syncthreads();

    {
        int tok = threadIdx.x >> 2, s8 = (threadIdx.x & 3) * 8;
        int nn = n0 + tok;
        int pp = ((win >> 2) * 48 + nn / 48) * 192 + (win & 3) * 48 + nn % 48;
        u32_t v0[4], v1[4];
        #pragma unroll
        for (int j = 0; j < 4; ++j) { v0[j] = Tt[tok][s8 + j]; v1[j] = Tt[tok][s8 + 4 + j]; }
        u32_t* d = (u32_t*)(refd + (size_t)pp * 64) + s8;
        *(uint4*)d       = uint4{v0[0], v0[1], v0[2], v0[3]};
        *(uint4*)(d + 4) = uint4{v1[0], v1[1], v1[2], v1[3]};
    }
}

// ------- conv3x3(+bias,relu)->out0, 1x1->out1, partition map; implicit-GEMM MFMA, NHWC in -------
__global__ __launch_bounds__(256) void conv_kernel(
    const u16_t* __restrict__ refined, const u16_t* __restrict__ Wpk,
    const float* __restrict__ b3, const float* __restrict__ w4, const float* __restrict__ b4,
    float* __restrict__ out0, float* __restrict__ out1, float* __restrict__ pm)
{
    __shared__ u16_t tile[3 * 50 * 64];    // [pix][ic], slot-swizzled; 19,200 B
    __shared__ float ps[48];
    int bid = (blockIdx.x & 7) * 96 + (blockIdx.x >> 3);
    const int y  = bid >> 2;
    const int x0 = (bid & 3) * 48;
    const int tid = threadIdx.x;
    if (tid < 48) ps[tid] = 0.f;

    for (int idx = tid; idx < 1200; idx += 256) {     // 150 pixels x 8 chunks
        int tg = idx & 7;
        int pix = idx >> 3;
        int r = pix / 50, cc = pix - r * 50;
        int yy = y - 1 + r, xg = x0 - 1 + cc;
        bf16x8 val = {0,0,0,0,0,0,0,0};
        if ((unsigned)yy < 192u && (unsigned)xg < 192u)
            val = *(const bf16x8*)(refined + ((size_t)(yy * 192 + xg)) * 64 + tg * 8);
        int slot = (tg + cc) & 7;
        *(bf16x8*)((char*)tile + (size_t)pix * 128 + slot * 16) = val;
    }
    __syncthreads();

    const int lane = tid & 63, mf = tid >> 6;
    const int ln = lane & 15, g = lane >> 4;

    bf16x8 wf[18];
    #pragma unroll
    for (int ks = 0; ks < 18; ++ks)
        wf[ks] = *(const bf16x8*)(Wpk + (size_t)((mf * 18 + ks) * 64 + lane) * 8);

    float b3v[4], w4v[4];
    #pragma unroll
    for (int r = 0; r < 4; ++r) { int oc = mf * 16 + 4 * g + r; b3v[r] = b3[oc]; w4v[r] = w4[oc]; }

    for (int nf = 0; nf < 3; ++nf) {
        int xl = nf * 16 + ln;
        f32x4 acc0 = {0.f,0.f,0.f,0.f}, acc1 = acc0;
        #pragma unroll
        for (int ks = 0; ks < 18; ++ks) {
            int tap = ks >> 1, icc = ks & 1;
            int dy = tap / 3, dx = tap - (tap / 3) * 3;
            int cc = xl + dx;
            int slot = (icc * 4 + g + cc) & 7;
            bf16x8 bfr = *(const bf16x8*)((const char*)tile + (size_t)(dy * 50 + cc) * 128 + slot * 16);
            if (ks & 1) acc1 = __builtin_amdgcn_mfma_f32_16x16x32_bf16(wf[ks], bfr, acc1, 0, 0, 0);
            else        acc0 = __builtin_amdgcn_mfma_f32_16x16x32_bf16(wf[ks], bfr, acc0, 0, 0, 0);
        }
        int xg = x0 + xl;
        float s4 = 0.f;
        #pragma unroll
        for (int r = 0; r < 4; ++r) {
            int oc = mf * 16 + 4 * g + r;
            float v = fmaxf(acc0[r] + acc1[r] + b3v[r], 0.f);
            out0[(size_t)oc * HW2 + y * 192 + xg] = v;
            s4 += v * w4v[r];
        }
        atomicAdd(&ps[xl], s4);
    }
    __syncthreads();
    if (tid < 48) {
        int xg = x0 + tid;
        out1[y * 192 + xg] = ps[tid] + b4[0];
        int ym = y % 48, xm = xg % 48;
        pm[y * 192 + xg] = ((ym == 0) | (ym == 47) | (xm == 0) | (xm == 47)) ? 0.6f : 1.0f;
    }
}

extern "C" void kernel_launch(void* const* d_in, const int* in_sizes, int n_in,
                              void* d_out, int out_size, void* d_ws, size_t ws_size,
                              hipStream_t stream)
{
    const float* x   = (const float*)d_in[0];
    const float* ref = (const float*)d_in[1];
    const float* unc = (const float*)d_in[2];
    const float* ipw = (const float*)d_in[3];
    const float* ipb = (const float*)d_in[4];
    const float* opw = (const float*)d_in[5];
    const float* opb = (const float*)d_in[6];
    const float* w1  = (const float*)d_in[7];
    const float* b1  = (const float*)d_in[8];
    const float* w3  = (const float*)d_in[9];
    const float* b3  = (const float*)d_in[10];
    const float* w4  = (const float*)d_in[11];
    const float* b4  = (const float*)d_in[12];

    char* ws = (char*)d_ws;
    u16_t* Qb    = (u16_t*)(ws);                  // 4,718,592
    u16_t* Kb    = (u16_t*)(ws + 4718592);        // 4,718,592
    u16_t* Vtb   = (u16_t*)(ws + 9437184);        // 4,718,592
    float* Ufp   = (float*)(ws + 14155776);       // 147,456
    float* meanV = (float*)(ws + 14303232);       // 4,096
    float* Wc    = (float*)(ws + 14307328);       // 16,384
    float* bc    = (float*)(ws + 14323712);       // 256
    u16_t* Wpk   = (u16_t*)(ws + 14323968);       // 73,728
    u16_t* Opart = (u16_t*)(ws + 14397696);       // 9,437,184  (2 halves x 36864 x 64 bf16)
    float* Lpart = (float*)(ws + 23834880);       // 294,912    (2 x 36864 f32)
    u16_t* refd  = (u16_t*)(ws + 24129792);       // 4,718,592  (total 28,848,384 B)

    float* out0 = (float*)d_out;                  // r3: [1,64,192,192]
    float* out1 = out0 + 2359296;                 // out: [1,1,192,192]
    float* pmap = out0 + 2396160;                 // partition_map

    proj_kernel   <<<1152, 256, 0, stream>>>(x, ref, unc, ipw, ipb, Qb, Kb, Vtb, Ufp);
    prepmv_kernel <<<101,  256, 0, stream>>>(opw, opb, w1, b1, w3, Vtb, Wc, bc, Wpk, meanV);
    attn_kernel   <<<1152, 256, 0, stream>>>(Qb, Kb, Vtb, Ufp, Opart, Lpart);
    refined_kernel<<<576,  256, 0, stream>>>(x, Opart, Lpart, Ufp, meanV, Wc, bc, refd);
    conv_kernel   <<<768,  256, 0, stream>>>(refd, Wpk, b3, w4, b4, out0, out1, pmap);
}